// Round 6
// baseline (80.317 us; speedup 1.0000x reference)
//
#include <hip/hip_runtime.h>
#include <math.h>

#define BATCH 4096
#define DIM 128
#define TWO_B 8192
// reps scaled by sqrt(2*log2(e)) so fp8 MFMA acc = 2*log2(e)*sim, and
// exp(sim/TEMP) = exp(2*sim) = exp2(acc) -> single native v_exp_f32.
#define SCALE 1.69864374f
#define NBLK 1024   // exactly 4 blocks/CU, co-resident by __launch_bounds__(256,4)
#define MAGIC 0x6D2F9A3Bu   // flag value; != workspace poison pattern (R17-proven)

typedef float floatx4 __attribute__((ext_vector_type(4)));
typedef int   intx4  __attribute__((ext_vector_type(4)));
typedef long  longx2 __attribute__((ext_vector_type(2)));

__device__ __forceinline__ longx2 as_l2(intx4 v) {
    union { intx4 a; longx2 b; } u; u.a = v; return u.b;
}
__device__ __forceinline__ unsigned char to_fp8(float v) {
    return (unsigned char)(__builtin_amdgcn_cvt_pk_fp8_f32(v, v, 0, false) & 0xff);
}
// Agent-scope (through-to-MALL, the coherent point) relaxed store/load helpers.
template <typename T>
__device__ __forceinline__ void st_agent(T* p, T v) {
    __hip_atomic_store(p, v, __ATOMIC_RELAXED, __HIP_MEMORY_SCOPE_AGENT);
}
template <typename T>
__device__ __forceinline__ T ld_agent(const T* p) {
    return __hip_atomic_load(p, __ATOMIC_RELAXED, __HIP_MEMORY_SCOPE_AGENT);
}

// FP8 fragment-native blocked layout (byte address):
//   addr(r,k) = (r>>4)*2048 + (k>>6)*1024 + ((k>>3)&3)*256 + (r&15)*16
//             + ((k>>5)&1)*8 + (k&7)
// A wave's 16-lane-group load at q*256 + lr*16 of 16B yields exactly the
// mfma_f32_16x16x32_fp8 A/B fragments for two K=32 chunks (1KB/instruction).

// R18: R17's fence-free fused kernel minus the MALL small-op storm.
// R17 residual (~16us over phase model) == 1.05M un-coalescable 1-byte agent
// stores (phase 1) + 1.06M f32 atomicAdd RMWs (phase 2 denom). Fixes:
//  - phase 1: LDS-stage the blocked fp8 bytes, write ONE coalesced 4B agent
//    store per thread (contiguous 256B per wave);
//  - phase 2: replace denom atomics with R13's exactly-once part[128][8192]
//    slot writes (one contiguous 4B agent store per lane for row-parts and
//    col-parts; no atomics, no zero-init);
//  - phase 3: distributed over 32 finisher blocks (bid>=992, the ones with
//    only 2 sim regions), plain cached strided reads of part (lines are
//    never stale: write-through-only, never previously cached), then
//    atomicAdd(out).
// Barrier protocol (flags + per-wave vmcnt drain at __syncthreads + MAGIC)
// is byte-identical to the PASSING R17.
__global__ __launch_bounds__(256, 4) void fused_kernel(const float* __restrict__ p1,
                                                       const float* __restrict__ p2,
                                                       unsigned char* __restrict__ repsF,
                                                       float* __restrict__ pos,
                                                       float* __restrict__ part,
                                                       unsigned int* __restrict__ gsync,
                                                       float* __restrict__ out) {
    __shared__ float lds[4][16][68];     // per-wave slab: phase-1 staging + phase-2 transpose
    int tid = threadIdx.x;
    int wid = tid >> 6, lane = tid & 63;
    int bid = blockIdx.x;
    unsigned int* arr  = gsync;              // [NBLK] phase-1 arrive flags
    unsigned int* done = gsync + NBLK;       // [NBLK] phase-2 arrive flags
    unsigned int* go   = gsync + 2 * NBLK;   // [1]    phase-1 broadcast

    // ---------------- Phase 1: L2-normalize -> fp8 blocked reps ----------------
    {
        int b = bid * 4 + wid;               // [0,4096)
        const float* r1 = p1 + (size_t)b * DIM;
        const float* r2 = p2 + (size_t)b * DIM;
        float x0 = r1[lane], x1 = r1[lane + 64];
        float y0 = r2[lane], y1 = r2[lane + 64];
        float s1 = x0 * x0 + x1 * x1;
        float s2 = y0 * y0 + y1 * y1;
        float s12 = x0 * y0 + x1 * y1;
        #pragma unroll
        for (int off = 32; off; off >>= 1) {
            s1  += __shfl_xor(s1, off);
            s2  += __shfl_xor(s2, off);
            s12 += __shfl_xor(s12, off);
        }
        float n1 = fmaxf(sqrtf(s1), 1e-12f);
        float n2 = fmaxf(sqrtf(s2), 1e-12f);
        float i1 = SCALE / n1;
        float i2 = SCALE / n2;

        if (lane == 0) st_agent(&pos[b], s12 / (n1 * n2));  // exact fp32 positive
        if (bid == 0 && tid == 0) st_agent(out, 0.0f);

        // Stage 2 rows (b and b+BATCH) x 128 fp8 bytes in LDS, mirroring the
        // blocked layout of the 16B segments: local = row'*128 + seg*16 + byte,
        // seg = h*4 + ((k>>3)&3), byte = ((k>>5)&1)*8 + (k&7).
        char* stg = (char*)&lds[wid][0][0];  // 256 B per wave, wave-local
        int s  = (lane >> 3) & 3;
        int byt = ((lane >> 5) & 1) * 8 + (lane & 7);
        stg[s * 16 + byt]             = to_fp8(x0 * i1);   // k = lane      (h=0)
        stg[(4 + s) * 16 + byt]       = to_fp8(x1 * i1);   // k = lane + 64 (h=1)
        stg[128 + s * 16 + byt]       = to_fp8(y0 * i2);
        stg[128 + (4 + s) * 16 + byt] = to_fp8(y1 * i2);
        asm volatile("s_waitcnt lgkmcnt(0)" ::: "memory");  // same-wave ds order

        // Read back one dword per lane, store coalesced (256B/wave contiguous
        // per 16B segment run) write-through to MALL.
        int rowp = lane >> 5, seg = (lane >> 2) & 7, q4 = lane & 3;
        unsigned int dw = *(const unsigned int*)(stg + rowp * 128 + seg * 16 + q4 * 4);
        int rr = rowp ? (b + BATCH) : b;
        size_t ga = (size_t)(rr >> 4) * 2048 + (rr & 15) * 16
                  + (seg >> 2) * 1024 + (seg & 3) * 256 + q4 * 4;
        st_agent((unsigned int*)(repsF + ga), dw);
    }

    // ---------------- Grid barrier A (flags only, no fences; R17-exact) --------
    __syncthreads();                         // per-wave vmcnt drain + barrier
    if (tid == 0) {
        asm volatile("s_waitcnt vmcnt(0)" ::: "memory");   // MALL acks in
        st_agent(&arr[bid], MAGIC);
    }
    if (bid == 0 && wid == 0) {              // checker: gather 16 flags/lane
        int guard = 0;
        for (;;) {
            int ok = 1;
            #pragma unroll
            for (int j = 0; j < 16; ++j)
                ok &= (ld_agent(&arr[lane + j * 64]) == MAGIC) ? 1 : 0;
            if (__all(ok) || ++guard > (1 << 20)) break;
            __builtin_amdgcn_s_sleep(2);
        }
        if (lane == 0) {
            asm volatile("s_waitcnt vmcnt(0)" ::: "memory");
            st_agent(go, MAGIC);
        }
    }
    if (tid == 0) {                          // wait: read-only poll, no RMW
        int guard = 0;
        while (ld_agent(go) != MAGIC && ++guard < (1 << 20))
            __builtin_amdgcn_s_sleep(2);
    }
    __syncthreads();
    asm volatile("" ::: "memory");           // no reordering across the barrier

    // ---------------- Phase 2: sim tiles (grid-stride over 2080 regions) -------
    {
        int wm = wid >> 1, wn = wid & 1;
        int lr = lane & 15, q = lane >> 4;
        const char* base = (const char*)repsF;
        int lofs = q * 256 + lr * 16;

        for (int t = bid; t < 65 * 32; t += NBLK) {
            int r = t / 65;                  // [0,32)
            int c = t - r * 65;              // [0,65)
            int TM, TN;
            if (c < 64 - r) { TM = r;      TN = r + c; }
            else            { TM = 63 - r; TN = TM + (c - (64 - r)); }
            if (TM == TN && wm == 1 && wn == 0) continue;   // mirror quadrant
            int tm = 2 * TM + wm, tn = 2 * TN + wn;         // tm <= tn guaranteed
            bool diag = (tm == tn);

            const char* ab = base + tm * 8192 + lofs;
            const char* bb = base + tn * 8192 + lofs;

            longx2 aF[4][2], bF[4][2];       // [idx][h]: .x = chunk 2h, .y = 2h+1
            #pragma unroll
            for (int mi = 0; mi < 4; ++mi)
                #pragma unroll
                for (int h = 0; h < 2; ++h) {
                    aF[mi][h] = as_l2(*(const intx4*)(ab + mi * 2048 + h * 1024));
                    bF[mi][h] = as_l2(*(const intx4*)(bb + mi * 2048 + h * 1024));
                }

            float cs[4] = {0.0f, 0.0f, 0.0f, 0.0f};
            floatx4 rpacc[4];                // row-partials per mi, across passes

            #pragma unroll
            for (int p = 0; p < 2; ++p) {    // ni-pass: cols 32p .. 32p+31
                floatx4 acc[4][2] = {};
                #pragma unroll
                for (int ck = 0; ck < 4; ++ck) { // K=32 chunks
                    int h = ck >> 1, sel = ck & 1;
                    #pragma unroll
                    for (int mi = 0; mi < 4; ++mi)
                        #pragma unroll
                        for (int nn = 0; nn < 2; ++nn)
                            acc[mi][nn] = __builtin_amdgcn_mfma_f32_16x16x32_fp8_fp8(
                                aF[mi][h][sel], bF[2 * p + nn][h][sel], acc[mi][nn], 0, 0, 0);
                }
                // C/D layout: col = lr + 16*(2p+nn), row = q*4+reg+16*mi.
                #pragma unroll
                for (int mi = 0; mi < 4; ++mi) {
                    #pragma unroll
                    for (int reg = 0; reg < 4; ++reg) {
                        float e0 = __builtin_amdgcn_exp2f(acc[mi][0][reg]);
                        float e1 = __builtin_amdgcn_exp2f(acc[mi][1][reg]);
                        if (diag && (q * 4 + reg) == lr) {
                            if (mi == 2 * p)     e0 = 0.0f;   // ni == mi diagonal
                            if (mi == 2 * p + 1) e1 = 0.0f;
                        }
                        cs[2 * p]     += e0;
                        cs[2 * p + 1] += e1;
                        float rsum = e0 + e1;
                        rpacc[mi][reg] = (p == 0) ? rsum : (rpacc[mi][reg] + rsum);
                    }
                }
            }

            // Row sums: wave-local LDS transpose, ONE coalesced 4B agent store
            // per lane into the exactly-once part slot (k=tn, cols tm*64..+63).
            float* myl = &lds[wid][0][0];    // [16][68] floats
            #pragma unroll
            for (int mi = 0; mi < 4; ++mi)
                *(floatx4*)&myl[lr * 68 + mi * 16 + q * 4] = rpacc[mi];
            asm volatile("s_waitcnt lgkmcnt(0)" ::: "memory");
            {
                float rs = 0.0f;
                #pragma unroll
                for (int j = 0; j < 16; ++j)
                    rs += myl[j * 68 + lane];   // bank = (4j+lane)%32 -> 2-way, free
                st_agent(&part[(size_t)tn * TWO_B + tm * 64 + lane], rs);
            }
            if (!diag) {
                #pragma unroll
                for (int ni = 0; ni < 4; ++ni) {
                    cs[ni] += __shfl_xor(cs[ni], 16);
                    cs[ni] += __shfl_xor(cs[ni], 32);
                }
                // col index = (lane>>4)*16 + (lane&15) == lane; branchless select
                // (no runtime-indexed array -> stays in registers, rule #20).
                float cv = (lane & 32) ? ((lane & 16) ? cs[3] : cs[2])
                                       : ((lane & 16) ? cs[1] : cs[0]);
                st_agent(&part[(size_t)tm * TWO_B + tn * 64 + lane], cv);
            }
        }
    }

    // ---------------- Barrier B: arrive flags; 32 finisher blocks --------------
    __syncthreads();                         // per-wave vmcnt drain (stores acked)
    if (tid == 0) {
        asm volatile("s_waitcnt vmcnt(0)" ::: "memory");
        st_agent(&done[bid], MAGIC);
    }
    if (bid < NBLK - 32) return;             // finishers = 992..1023 (2-region blocks)
    if (wid == 0) {                          // each finisher waits for everyone
        int guard = 0;
        for (;;) {
            int ok = 1;
            #pragma unroll
            for (int j = 0; j < 16; ++j)
                ok &= (ld_agent(&done[lane + j * 64]) == MAGIC) ? 1 : 0;
            if (__all(ok) || ++guard > (1 << 20)) break;
            __builtin_amdgcn_s_sleep(2);
        }
    }
    __syncthreads();
    asm volatile("" ::: "memory");

    // ---------------- Phase 3: finish (32 blocks x 256 rows) -------------------
    {
        int r = (bid - (NBLK - 32)) * 256 + tid;      // [0,8192)
        const float* pk = part + r;
        float s0 = 0.0f, s1 = 0.0f, s2 = 0.0f, s3 = 0.0f;
        #pragma unroll
        for (int k = 0; k < 128; k += 4) {
            s0 += pk[(size_t)(k + 0) * TWO_B];
            s1 += pk[(size_t)(k + 1) * TWO_B];
            s2 += pk[(size_t)(k + 2) * TWO_B];
            s3 += pk[(size_t)(k + 3) * TWO_B];
        }
        float v = __logf((s0 + s1) + (s2 + s3)) - 2.0f * pos[r & (BATCH - 1)];
        #pragma unroll
        for (int off = 32; off; off >>= 1) v += __shfl_xor(v, off);
        if (lane == 0) atomicAdd(out, v * (1.0f / TWO_B));
    }
}

extern "C" void kernel_launch(void* const* d_in, const int* in_sizes, int n_in,
                              void* d_out, int out_size, void* d_ws, size_t ws_size,
                              hipStream_t stream) {
    const float* p1 = (const float*)d_in[0];
    const float* p2 = (const float*)d_in[1];
    float* out = (float*)d_out;

    char* ws = (char*)d_ws;
    unsigned char* repsF = (unsigned char*)ws;                 // 1 MB
    float* pos   = (float*)(ws + (size_t)TWO_B * DIM);         // 16 KB
    float* part  = pos + BATCH;                                // 4 MB
    unsigned int* gsync = (unsigned int*)(part + (size_t)128 * TWO_B);  // 8.2 KB

    fused_kernel<<<NBLK, 256, 0, stream>>>(p1, p2, repsF, pos, part, gsync, out);
}